// Round 10
// baseline (448.412 us; speedup 1.0000x reference)
//
#include <hip/hip_runtime.h>

typedef unsigned short u16;
typedef __attribute__((ext_vector_type(8))) short bf16x8;
typedef __attribute__((ext_vector_type(4))) float f32x4;
typedef __attribute__((ext_vector_type(4))) u16 u16x4;

#define T_TOK 16384
#define D_DIM 1024
#define NE 8
#define MAXP 33792   // max padded compact rows: 2*T + 8*128

__device__ __forceinline__ u16 f2bf(float f) {
  union { float f; unsigned int u; } c; c.f = f;
  unsigned int u = c.u;
  u += 0x7fffu + ((u >> 16) & 1u);   // round-to-nearest-even
  return (u16)(u >> 16);
}

__device__ __forceinline__ float bf2f(u16 v) {
  union { unsigned int u; float f; } c; c.u = ((unsigned int)v) << 16;
  return c.f;
}

__device__ __forceinline__ float gelu_exact(float u) {
  return 0.5f * u * (1.0f + erff(u * 0.70710678118654752f));
}

__device__ __forceinline__ float rdlane(float v, int l) {
  union { float f; int i; } c; c.f = v;
  union { int i; float f; } d;
  d.i = __builtin_amdgcn_readlane(c.i, l);
  return d.f;
}

__device__ __forceinline__ void gld16(const void* g, void* l) {
  __builtin_amdgcn_global_load_lds(
      (const __attribute__((address_space(1))) unsigned int*)g,
      (__attribute__((address_space(3))) unsigned int*)l, 16, 0, 0);
}

// Stage a 128-row x 64-col bf16 tile (contiguous rows) into linear LDS [128][64].
__device__ __forceinline__ void stage_tile(u16* lds, const char* g0, size_t stride,
                                           int wid, int lane) {
  const char* g = g0 + (size_t)(wid * 8 + (lane >> 3)) * stride + (size_t)((lane & 7) * 16);
  char* l = (char*)lds + wid * 1024;   // wave-uniform LDS base; HW adds lane*16
  #pragma unroll
  for (int c = 0; c < 4; ++c)
    gld16(g + (size_t)(32 * c) * stride, l + c * 4096);
}

// One BK=64 step: 32 MFMA per wave, acc[4][4] (64x64 per wave, 2x2 waves = 128x128)
__device__ __forceinline__ void mma_step(const u16* As, const u16* Bs, f32x4 acc[4][4],
                                         int wm, int wn, int lane) {
  const int r = lane & 15, kq = (lane >> 4) * 8;
  #pragma unroll
  for (int ks = 0; ks < 2; ++ks) {
    const int col = ks * 32 + kq;
    bf16x8 a[4], b[4];
    #pragma unroll
    for (int mf = 0; mf < 4; ++mf)
      a[mf] = *(const bf16x8*)&As[(wm * 64 + mf * 16 + r) * 64 + col];
    #pragma unroll
    for (int nf = 0; nf < 4; ++nf)
      b[nf] = *(const bf16x8*)&Bs[(wn * 64 + nf * 16 + r) * 64 + col];
    #pragma unroll
    for (int mf = 0; mf < 4; ++mf)
      #pragma unroll
      for (int nf = 0; nf < 4; ++nf)
        acc[mf][nf] = __builtin_amdgcn_mfma_f32_16x16x32_bf16(a[mf], b[nf], acc[mf][nf], 0, 0, 0);
  }
}

// ---------------- tiled transpose+convert: in[e][R][C] f32 -> out[e][C][R] bf16 ----------------
__global__ __launch_bounds__(256) void transpose_cvt_kernel(const float* __restrict__ in,
                                                            u16* __restrict__ out,
                                                            int R, int C) {
  __shared__ u16 t[32][36];
  const int e = blockIdx.z;
  const int r0 = blockIdx.x * 32, c0 = blockIdx.y * 32;
  const int tid = threadIdx.x;
  {
    const int r = tid >> 3, cq = (tid & 7) * 4;
    float4 v = *(const float4*)(in + ((size_t)e * R + r0 + r) * C + c0 + cq);
    t[r][cq + 0] = f2bf(v.x); t[r][cq + 1] = f2bf(v.y);
    t[r][cq + 2] = f2bf(v.z); t[r][cq + 3] = f2bf(v.w);
  }
  __syncthreads();
  {
    const int c = tid >> 3, rq = (tid & 7) * 4;
    u16x4 o;
    o.x = t[rq + 0][c]; o.y = t[rq + 1][c]; o.z = t[rq + 2][c]; o.w = t[rq + 3][c];
    *(u16x4*)(out + ((size_t)e * C + c0 + c) * R + r0 + rq) = o;
  }
}

// ---------------- gating phase 1: partial GEMM1 over a K-quarter (readlane-A) ----------------
// grid (512, 4): blockIdx.x = token block (32 tokens), blockIdx.y = K-quarter (256 K).
// Wave w owns tokens t0+8w..+7 (wave-uniform A via v_readlane -> SGPR operand);
// lane owns cols lane*4..+3. Per kk: 1 ds_read_b128 (B) + 8 readlane + 32 FMA.
// Bs [2][8][256] f32 double-buffered via global_load_lds; x loaded as one coalesced
// float4 per 32-K window per thread (lanes 0..7 = 32 consecutive k of one token).
__global__ __launch_bounds__(256, 4) void gating_p1_kernel(
    const float* __restrict__ x, const float* __restrict__ wg1,
    u16* __restrict__ xb, float* __restrict__ p_buf) {
  __shared__ float Bs[2][8 * 256];
  const int tid = threadIdx.x;
  const int lane = tid & 63, w = tid >> 6;
  const int t0 = blockIdx.x * 32;
  const int kbeg = blockIdx.y * 256;
  const int srow = tid >> 3, sc4 = (tid & 7) * 4;   // token row / k-quad within window

  float acc[8][4];
  #pragma unroll
  for (int i = 0; i < 8; ++i)
    #pragma unroll
    for (int j = 0; j < 4; ++j) acc[i][j] = 0.f;

  // prologue: stage Bs slab 0 (k rows kbeg..kbeg+7); load x window 0
  {
    const char* g = (const char*)wg1 + (size_t)(kbeg + w * 2) * 1024 + lane * 16;
    char* l = (char*)&Bs[0][0] + w * 2048;
    gld16(g, l);
    gld16(g + 1024, l + 1024);
  }
  float4 xq = *(const float4*)(x + (size_t)(t0 + srow) * 1024 + kbeg + sc4);
  __syncthreads();

  for (int win = 0; win < 8; ++win) {
    // emit bf16 x for this window (held in xq)
    {
      u16x4 o; o.x = f2bf(xq.x); o.y = f2bf(xq.y); o.z = f2bf(xq.z); o.w = f2bf(xq.w);
      *(u16x4*)(xb + (size_t)(t0 + srow) * 1024 + kbeg + win * 32 + sc4) = o;
    }
    // prefetch next window's x
    float4 xqn = xq;
    if (win < 7)
      xqn = *(const float4*)(x + (size_t)(t0 + srow) * 1024 + kbeg + (win + 1) * 32 + sc4);

    const float xv[4] = {xq.x, xq.y, xq.z, xq.w};
    #pragma unroll
    for (int sub = 0; sub < 4; ++sub) {
      const int ksub = win * 4 + sub;          // 0..31
      if (ksub + 1 < 32) {                     // stage next slab into other buffer
        const char* g = (const char*)wg1 +
            (size_t)(kbeg + (ksub + 1) * 8 + w * 2) * 1024 + lane * 16;
        char* l = (char*)&Bs[(sub & 1) ^ 1][0] + w * 2048;
        gld16(g, l);
        gld16(g + 1024, l + 1024);
      }
      #pragma unroll
      for (int kk = 0; kk < 8; ++kk) {
        const int kw = sub * 8 + kk;           // k within window, compile-time
        float4 b = *(const float4*)&Bs[sub & 1][kk * 256 + lane * 4];
        float s[8];
        #pragma unroll
        for (int i = 0; i < 8; ++i)
          s[i] = rdlane(xv[kw & 3], i * 8 + (kw >> 2));
        #pragma unroll
        for (int i = 0; i < 8; ++i) {
          acc[i][0] += s[i] * b.x; acc[i][1] += s[i] * b.y;
          acc[i][2] += s[i] * b.z; acc[i][3] += s[i] * b.w;
        }
      }
      __syncthreads();
    }
    xq = xqn;
  }

  // store partials: p_buf[kq][t][col], coalesced 1KB per i
  #pragma unroll
  for (int i = 0; i < 8; ++i) {
    float* p = &p_buf[((size_t)blockIdx.y * T_TOK + t0 + w * 8 + i) * 256];
    *(float4*)&p[lane * 4] = make_float4(acc[i][0], acc[i][1], acc[i][2], acc[i][3]);
  }
}

// ---------------- gating phase 2: combine 4 partials + gelu + GEMM2 + softmax + top2 ----------------
__global__ __launch_bounds__(256) void gating_p2_kernel(
    const float* __restrict__ p_buf, const float* __restrict__ bg1,
    const float* __restrict__ wg2, const float* __restrict__ bg2,
    int* __restrict__ top_i, float2* __restrict__ top_g) {
  const int tid = threadIdx.x;
  const int tn = tid & 31, tm = tid >> 5;
  const int t0 = blockIdx.x * 32;

  float bb[8];
  {
    float4 ba = *(const float4*)&bg1[tn * 4];
    float4 bc = *(const float4*)&bg1[128 + tn * 4];
    bb[0] = ba.x; bb[1] = ba.y; bb[2] = ba.z; bb[3] = ba.w;
    bb[4] = bc.x; bb[5] = bc.y; bb[6] = bc.z; bb[7] = bc.w;
  }

  // h values for this thread's 4 tokens x 8 cols
  float hv[4][8];
  #pragma unroll
  for (int i = 0; i < 4; ++i) {
    const size_t t = t0 + tm * 4 + i;
    float s[8];
    #pragma unroll
    for (int j = 0; j < 8; ++j) s[j] = 0.f;
    #pragma unroll
    for (int q = 0; q < 4; ++q) {
      const float* p = &p_buf[((size_t)q * T_TOK + t) * 256];
      float4 a0 = *(const float4*)&p[tn * 4];
      float4 a1 = *(const float4*)&p[128 + tn * 4];
      s[0] += a0.x; s[1] += a0.y; s[2] += a0.z; s[3] += a0.w;
      s[4] += a1.x; s[5] += a1.y; s[6] += a1.z; s[7] += a1.w;
    }
    #pragma unroll
    for (int j = 0; j < 8; ++j) hv[i][j] = gelu_exact(s[j] + bb[j]);
  }

  float part[4][8];
  #pragma unroll
  for (int i = 0; i < 4; ++i)
    #pragma unroll
    for (int e = 0; e < 8; ++e) part[i][e] = 0.f;
  #pragma unroll
  for (int j = 0; j < 8; ++j) {
    const int col = (j < 4) ? (tn * 4 + j) : (128 + tn * 4 + (j - 4));
    float4 wa = *(const float4*)&wg2[col * 8];
    float4 wb = *(const float4*)&wg2[col * 8 + 4];
    float we[8] = {wa.x, wa.y, wa.z, wa.w, wb.x, wb.y, wb.z, wb.w};
    #pragma unroll
    for (int i = 0; i < 4; ++i)
      #pragma unroll
      for (int e = 0; e < 8; ++e) part[i][e] += hv[i][j] * we[e];
  }
  #pragma unroll
  for (int mask = 1; mask < 32; mask <<= 1)
    #pragma unroll
    for (int i = 0; i < 4; ++i)
      #pragma unroll
      for (int e = 0; e < 8; ++e) part[i][e] += __shfl_xor(part[i][e], mask);

  if (tn < 4) {
    float lg[8];
    #pragma unroll
    for (int i = 0; i < 4; ++i)
      if (tn == i) {
        #pragma unroll
        for (int e = 0; e < 8; ++e) lg[e] = part[i][e];
      }
    #pragma unroll
    for (int e = 0; e < 8; ++e) lg[e] += bg2[e];
    float m = lg[0];
    #pragma unroll
    for (int e = 1; e < 8; ++e) m = fmaxf(m, lg[e]);
    float ex[8], s = 0.f;
    #pragma unroll
    for (int e = 0; e < 8; ++e) { ex[e] = expf(lg[e] - m); s += ex[e]; }
    int i1 = 0;
    #pragma unroll
    for (int e = 1; e < 8; ++e) if (lg[e] > lg[i1]) i1 = e;   // strict >: lowest idx on tie
    int i2 = (i1 == 0) ? 1 : 0;
    #pragma unroll
    for (int e = 0; e < 8; ++e) if (e != i1 && lg[e] > lg[i2]) i2 = e;
    float inv = 1.f / s;
    const int t = t0 + tm * 4 + tn;
    top_i[t] = i1 | (i2 << 8);
    top_g[t] = make_float2(ex[i1] * inv, ex[i2] * inv);
  }
}

// ---------------- hist: per-256-token-chunk expert histogram (LDS atomics only) ----------------
__global__ __launch_bounds__(256) void hist_kernel(const int* __restrict__ top_i,
                                                   int* __restrict__ hist) {
  __shared__ int h[NE];
  const int tid = threadIdx.x;
  if (tid < NE) h[tid] = 0;
  __syncthreads();
  const int ti = top_i[blockIdx.x * 256 + tid];
  atomicAdd(&h[ti & 255], 1);
  atomicAdd(&h[ti >> 8], 1);
  __syncthreads();
  if (tid < NE) hist[blockIdx.x * NE + tid] = h[tid];
}

// ---------------- scan: totals, padded offsets, per-chunk bases (single block) ----------------
__global__ __launch_bounds__(64) void scan_kernel(const int* __restrict__ hist,
                                                  int* __restrict__ cnt,
                                                  int* __restrict__ offs,
                                                  int* __restrict__ cbase) {
  __shared__ int tot[NE], off_s[NE];
  const int tid = threadIdx.x;
  if (tid < NE) {
    int s = 0;
    for (int c = 0; c < 64; ++c) s += hist[c * NE + tid];
    tot[tid] = s; cnt[tid] = s;
  }
  __syncthreads();
  if (tid == 0) {
    int o = 0;
    #pragma unroll
    for (int e = 0; e < NE; ++e) { off_s[e] = o; o += (tot[e] + 127) & ~127; }
  }
  __syncthreads();
  if (tid < NE) {
    offs[tid] = off_s[tid];
    int r = off_s[tid];
    for (int c = 0; c < 64; ++c) { cbase[c * NE + tid] = r; r += hist[c * NE + tid]; }
  }
}

// ---------------- fill: scatter tokens into per-expert compact lists (LDS atomics) ----------------
__global__ __launch_bounds__(256) void fill_kernel(
    const int* __restrict__ top_i, const int* __restrict__ cbase,
    int* __restrict__ tok_list, int* __restrict__ pos1, int* __restrict__ pos2) {
  __shared__ int lcnt[NE];
  const int tid = threadIdx.x;
  if (tid < NE) lcnt[tid] = 0;
  __syncthreads();
  const int t = blockIdx.x * 256 + tid;
  const int ti = top_i[t];
  const int i1 = ti & 255, i2 = ti >> 8;
  const int r1 = atomicAdd(&lcnt[i1], 1);
  const int r2 = atomicAdd(&lcnt[i2], 1);
  const int p1 = cbase[blockIdx.x * NE + i1] + r1;
  const int p2 = cbase[blockIdx.x * NE + i2] + r2;
  tok_list[p1] = t; tok_list[p2] = t;
  pos1[t] = p1; pos2[t] = p2;
}

// ---------------- pass A (compact): h[p][h] = gelu(x[tok[p]] @ W1e + b1e), bf16 ----------------
__global__ __launch_bounds__(256) void expert_h_kernel(
    const u16* __restrict__ xb, const u16* __restrict__ w1t,
    const float* __restrict__ b1, const int* __restrict__ tok_list,
    const int* __restrict__ cnt, const int* __restrict__ offs,
    u16* __restrict__ h_c) {
  __shared__ u16 As[128 * 64];
  __shared__ u16 Bs[128 * 64];
  __shared__ float b1_s[128];
  const int e = blockIdx.z;
  const int nblk = (cnt[e] + 127) >> 7;
  if ((int)blockIdx.x >= nblk) return;
  const int tid = threadIdx.x, lane = tid & 63, wid = tid >> 6;
  const int base = offs[e] + blockIdx.x * 128;
  const int n0 = blockIdx.y * 128;
  const int wm = wid >> 1, wn = wid & 1;

  if (tid < 128) b1_s[tid] = b1[e * 256 + n0 + tid];

  // token ids for this wave's staged rows (hoisted out of the K loop)
  int tk[4];
  {
    const int r0 = wid * 8 + (lane >> 3);
    #pragma unroll
    for (int c = 0; c < 4; ++c) tk[c] = tok_list[base + r0 + 32 * c];
  }

  f32x4 acc[4][4];
  #pragma unroll
  for (int i = 0; i < 4; ++i)
    #pragma unroll
    for (int j = 0; j < 4; ++j) acc[i][j] = (f32x4){0.f, 0.f, 0.f, 0.f};

  const char* Bb = (const char*)w1t + ((size_t)e * 256 + n0) * 2048;
  const int cb = (lane & 7) * 16;
  for (int kt = 0; kt < 16; ++kt) {
    __syncthreads();
    {   // gather-stage A: per-lane global row = tok_list row
      char* l = (char*)As + wid * 1024;
      #pragma unroll
      for (int c = 0; c < 4; ++c)
        gld16((const char*)xb + (size_t)tk[c] * 2048 + kt * 128 + cb, l + c * 4096);
    }
    stage_tile(Bs, Bb + kt * 128, 2048, wid, lane);
    __syncthreads();
    mma_step(As, Bs, acc, wm, wn, lane);
  }

  #pragma unroll
  for (int mf = 0; mf < 4; ++mf)
    #pragma unroll
    for (int rr = 0; rr < 4; ++rr) {
      const int lt = wm * 64 + mf * 16 + ((lane >> 4) << 2) + rr;
      #pragma unroll
      for (int nf = 0; nf < 4; ++nf) {
        const int ln = wn * 64 + nf * 16 + (lane & 15);
        float u = acc[mf][nf][rr] + b1_s[ln];
        h_c[(size_t)(base + lt) * 256 + n0 + ln] = f2bf(gelu_exact(u));
      }
    }
}

// ---------------- pass B (compact): o[p][d] = h[p] @ W2e + b2e, bf16 ----------------
__global__ __launch_bounds__(256) void moe_out_kernel(
    const u16* __restrict__ h_c, const u16* __restrict__ w2t,
    const float* __restrict__ b2, const int* __restrict__ cnt,
    const int* __restrict__ offs, u16* __restrict__ o_c) {
  __shared__ u16 As[128 * 64];
  __shared__ u16 Bs[128 * 64];
  __shared__ float b2_s[128];
  const int e = blockIdx.z;
  const int nblk = (cnt[e] + 127) >> 7;
  if ((int)blockIdx.x >= nblk) return;
  const int tid = threadIdx.x, lane = tid & 63, wid = tid >> 6;
  const int base = offs[e] + blockIdx.x * 128;
  const int n0 = blockIdx.y * 128;
  const int wm = wid >> 1, wn = wid & 1;

  if (tid < 128) b2_s[tid] = b2[(size_t)e * 1024 + n0 + tid];

  f32x4 acc[4][4];
  #pragma unroll
  for (int i = 0; i < 4; ++i)
    #pragma unroll
    for (int j = 0; j < 4; ++j) acc[i][j] = (f32x4){0.f, 0.f, 0.f, 0.f};

  const char* Ab = (const char*)h_c + (size_t)base * 512;
  const char* Bb = (const char*)w2t + ((size_t)e * D_DIM + n0) * 512;
  #pragma unroll 1
  for (int kt = 0; kt < 4; ++kt) {
    __syncthreads();
    stage_tile(As, Ab + kt * 128, 512, wid, lane);
    stage_tile(Bs, Bb + kt * 128, 512, wid, lane);
    __syncthreads();
    mma_step(As, Bs, acc, wm, wn, lane);
  }

  #pragma unroll
  for (int mf = 0; mf < 4; ++mf)
    #pragma unroll
    for (int rr = 0; rr < 4; ++rr) {
      const int lt = wm * 64 + mf * 16 + ((lane >> 4) << 2) + rr;
      #pragma unroll
      for (int nf = 0; nf < 4; ++nf) {
        const int ln = wn * 64 + nf * 16 + (lane & 15);
        o_c[(size_t)(base + lt) * 1024 + n0 + ln] = f2bf(acc[mf][nf][rr] + b2_s[ln]);
      }
    }
}

// ---------------- gather: y[t] = g1*o[p1] + g2*o[p2] ----------------
__global__ __launch_bounds__(256) void gather_kernel(
    const u16* __restrict__ o_c, const int* __restrict__ pos1,
    const int* __restrict__ pos2, const float2* __restrict__ top_g,
    float* __restrict__ y) {
  const int t = blockIdx.x;
  const int p1 = pos1[t], p2 = pos2[t];
  const float2 g = top_g[t];
  const int c = threadIdx.x * 4;
  u16x4 a = *(const u16x4*)&o_c[(size_t)p1 * 1024 + c];
  u16x4 b = *(const u16x4*)&o_c[(size_t)p2 * 1024 + c];
  float4 o;
  o.x = g.x * bf2f(a.x) + g.y * bf2f(b.x);
  o.y = g.x * bf2f(a.y) + g.y * bf2f(b.y);
  o.z = g.x * bf2f(a.z) + g.y * bf2f(b.z);
  o.w = g.x * bf2f(a.w) + g.y * bf2f(b.w);
  *(float4*)&y[(size_t)t * 1024 + c] = o;
}

extern "C" void kernel_launch(void* const* d_in, const int* in_sizes, int n_in,
                              void* d_out, int out_size, void* d_ws, size_t ws_size,
                              hipStream_t stream) {
  (void)in_sizes; (void)n_in; (void)out_size; (void)ws_size;
  const float* x   = (const float*)d_in[0];
  const float* wg1 = (const float*)d_in[1];
  const float* bg1 = (const float*)d_in[2];
  const float* wg2 = (const float*)d_in[3];
  const float* bg2 = (const float*)d_in[4];
  const float* w1  = (const float*)d_in[5];
  const float* b1  = (const float*)d_in[6];
  const float* w2  = (const float*)d_in[7];
  const float* b2  = (const float*)d_in[8];
  float* y = (float*)d_out;

  char* ws = (char*)d_ws;
  u16* xb   = (u16*)(ws);                 // 33,554,432 B
  u16* w1t  = (u16*)(ws + 33554432);      //  4,194,304 B
  u16* w2t  = (u16*)(ws + 37748736);      //  4,194,304 B
  char* M   = ws + 41943040;              // metadata block
  int*    cnt      = (int*)(M);                 // 32 B
  int*    offs     = (int*)(M + 64);            // 32 B
  int*    hist     = (int*)(M + 128);           // 2,048 B
  int*    cbase    = (int*)(M + 2304);          // 2,048 B
  int*    tok_list = (int*)(M + 4608);          // 135,168 B -> ends M+139,776
  int*    top_i    = (int*)(M + 139776);        // 65,536 B
  float2* top_g    = (float2*)(M + 205312);     // 131,072 B
  int*    pos1     = (int*)(M + 336384);        // 65,536 B
  int*    pos2     = (int*)(M + 401920);        // 65,536 B -> ends M+467,456
  u16* h_c = (u16*)(ws + 42467328);       // MAXP*256*2 = 17,301,504 B
  u16* o_c = (u16*)(ws + 59768832);       // MAXP*1024*2 = 69,206,016 B (total ~123 MiB)
  // p_buf [4][T][256] f32 = 67,108,864 B aliased onto o_c: dead before moe_out writes o_c
  float* p_buf = (float*)(ws + 59768832);

  // zero tok_list (pad slots -> token 0); everything else fully overwritten each call
  hipMemsetAsync(tok_list, 0, 135168, stream);
  transpose_cvt_kernel<<<dim3(32, 8, 8), 256, 0, stream>>>(w1, w1t, 1024, 256);
  transpose_cvt_kernel<<<dim3(8, 32, 8), 256, 0, stream>>>(w2, w2t, 256, 1024);
  gating_p1_kernel<<<dim3(512, 4), 256, 0, stream>>>(x, wg1, xb, p_buf);
  gating_p2_kernel<<<512, 256, 0, stream>>>(p_buf, bg1, wg2, bg2, top_i, top_g);
  hist_kernel<<<64, 256, 0, stream>>>(top_i, hist);
  scan_kernel<<<1, 64, 0, stream>>>(hist, cnt, offs, cbase);
  fill_kernel<<<64, 256, 0, stream>>>(top_i, cbase, tok_list, pos1, pos2);
  expert_h_kernel<<<dim3(128, 2, 8), 256, 0, stream>>>(xb, w1t, b1, tok_list, cnt, offs, h_c);
  moe_out_kernel <<<dim3(128, 8, 8), 256, 0, stream>>>(h_c, w2t, b2, cnt, offs, o_c);
  gather_kernel  <<<16384, 256, 0, stream>>>(o_c, pos1, pos2, top_g, y);
}

// Round 11
// 208.543 us; speedup vs baseline: 2.1502x; 2.1502x over previous
//
#include <hip/hip_runtime.h>

typedef unsigned short u16;
typedef __attribute__((ext_vector_type(8))) short bf16x8;
typedef __attribute__((ext_vector_type(4))) float f32x4;
typedef __attribute__((ext_vector_type(4))) u16 u16x4;

#define T_TOK 16384
#define D_DIM 1024
#define NE 8
#define MAXP 33792   // max padded compact rows: 2*T + 8*128

__device__ __forceinline__ u16 f2bf(float f) {
  union { float f; unsigned int u; } c; c.f = f;
  unsigned int u = c.u;
  u += 0x7fffu + ((u >> 16) & 1u);   // round-to-nearest-even
  return (u16)(u >> 16);
}

__device__ __forceinline__ float bf2f(u16 v) {
  union { unsigned int u; float f; } c; c.u = ((unsigned int)v) << 16;
  return c.f;
}

__device__ __forceinline__ float gelu_exact(float u) {
  return 0.5f * u * (1.0f + erff(u * 0.70710678118654752f));
}

__device__ __forceinline__ void gld16(const void* g, void* l) {
  __builtin_amdgcn_global_load_lds(
      (const __attribute__((address_space(1))) unsigned int*)g,
      (__attribute__((address_space(3))) unsigned int*)l, 16, 0, 0);
}

// Stage a 128-row x 64-col bf16 tile (contiguous rows) into linear LDS [128][64].
__device__ __forceinline__ void stage_tile(u16* lds, const char* g0, size_t stride,
                                           int wid, int lane) {
  const char* g = g0 + (size_t)(wid * 8 + (lane >> 3)) * stride + (size_t)((lane & 7) * 16);
  char* l = (char*)lds + wid * 1024;   // wave-uniform LDS base; HW adds lane*16
  #pragma unroll
  for (int c = 0; c < 4; ++c)
    gld16(g + (size_t)(32 * c) * stride, l + c * 4096);
}

// Stage a 128-row x 32-col bf16 tile (row stride 1024 bf16) into linear LDS [128][32].
__device__ __forceinline__ void stage_b32(u16* lds, const u16* mat, int rowbase,
                                          int k0, int wid, int lane) {
  const char* g0 = (const char*)(mat + (size_t)rowbase * 1024 + k0);
  #pragma unroll
  for (int c = 0; c < 2; ++c) {
    const int row = c * 64 + wid * 16 + (lane >> 2);
    const char* g = g0 + (size_t)row * 2048 + (size_t)((lane & 3) * 16);
    char* l = (char*)lds + c * 4096 + wid * 1024;   // + lane*16 by HW
    gld16(g, l);
  }
}

// One BK=64 step: 32 MFMA per wave, acc[4][4] (64x64 per wave, 2x2 waves = 128x128)
__device__ __forceinline__ void mma_step(const u16* As, const u16* Bs, f32x4 acc[4][4],
                                         int wm, int wn, int lane) {
  const int r = lane & 15, kq = (lane >> 4) * 8;
  #pragma unroll
  for (int ks = 0; ks < 2; ++ks) {
    const int col = ks * 32 + kq;
    bf16x8 a[4], b[4];
    #pragma unroll
    for (int mf = 0; mf < 4; ++mf)
      a[mf] = *(const bf16x8*)&As[(wm * 64 + mf * 16 + r) * 64 + col];
    #pragma unroll
    for (int nf = 0; nf < 4; ++nf)
      b[nf] = *(const bf16x8*)&Bs[(wn * 64 + nf * 16 + r) * 64 + col];
    #pragma unroll
    for (int mf = 0; mf < 4; ++mf)
      #pragma unroll
      for (int nf = 0; nf < 4; ++nf)
        acc[mf][nf] = __builtin_amdgcn_mfma_f32_16x16x32_bf16(a[mf], b[nf], acc[mf][nf], 0, 0, 0);
  }
}

// ---------------- tiled transpose+convert: in[e][R][C] f32 -> out[e][C][R] bf16 ----------------
__global__ __launch_bounds__(256) void transpose_cvt_kernel(const float* __restrict__ in,
                                                            u16* __restrict__ out,
                                                            int R, int C) {
  __shared__ u16 t[32][36];
  const int e = blockIdx.z;
  const int r0 = blockIdx.x * 32, c0 = blockIdx.y * 32;
  const int tid = threadIdx.x;
  {
    const int r = tid >> 3, cq = (tid & 7) * 4;
    float4 v = *(const float4*)(in + ((size_t)e * R + r0 + r) * C + c0 + cq);
    t[r][cq + 0] = f2bf(v.x); t[r][cq + 1] = f2bf(v.y);
    t[r][cq + 2] = f2bf(v.z); t[r][cq + 3] = f2bf(v.w);
  }
  __syncthreads();
  {
    const int c = tid >> 3, rq = (tid & 7) * 4;
    u16x4 o;
    o.x = t[rq + 0][c]; o.y = t[rq + 1][c]; o.z = t[rq + 2][c]; o.w = t[rq + 3][c];
    *(u16x4*)(out + ((size_t)e * C + c0 + c) * R + r0 + rq) = o;
  }
}

// ---------------- transpose+split-convert: in[R][C] f32 -> hi/lo [C][R] bf16 ----------------
__global__ __launch_bounds__(256) void transpose_hilo_kernel(const float* __restrict__ in,
                                                             u16* __restrict__ out_hi,
                                                             u16* __restrict__ out_lo,
                                                             int R, int C) {
  __shared__ u16 th[32][36];
  __shared__ u16 tl[32][36];
  const int r0 = blockIdx.x * 32, c0 = blockIdx.y * 32;
  const int tid = threadIdx.x;
  {
    const int r = tid >> 3, cq = (tid & 7) * 4;
    float4 v = *(const float4*)(in + (size_t)(r0 + r) * C + c0 + cq);
    float vv[4] = {v.x, v.y, v.z, v.w};
    #pragma unroll
    for (int i = 0; i < 4; ++i) {
      u16 h = f2bf(vv[i]);
      th[r][cq + i] = h;
      tl[r][cq + i] = f2bf(vv[i] - bf2f(h));
    }
  }
  __syncthreads();
  {
    const int c = tid >> 3, rq = (tid & 7) * 4;
    u16x4 oh, ol;
    oh.x = th[rq + 0][c]; oh.y = th[rq + 1][c]; oh.z = th[rq + 2][c]; oh.w = th[rq + 3][c];
    ol.x = tl[rq + 0][c]; ol.y = tl[rq + 1][c]; ol.z = tl[rq + 2][c]; ol.w = tl[rq + 3][c];
    *(u16x4*)(out_hi + (size_t)(c0 + c) * R + r0 + rq) = oh;
    *(u16x4*)(out_lo + (size_t)(c0 + c) * R + r0 + rq) = ol;
  }
}

// ---------------- gating GEMM1 via split-bf16 MFMA (3-term) ----------------
// grid (128, 2): 128x128 tile of p = x @ wg1 (no bias). BK=32 double-buffered.
// A (x) reg-staged with on-the-fly hi/lo split; emits xb (= x_hi) when blockIdx.y==0.
// B from pre-transposed wg1t_hi/lo [256][1024]. acc = Ah*Bh + Ah*Bl + Al*Bh (fp32).
__global__ __launch_bounds__(256) void gating_mfma_kernel(
    const float* __restrict__ x, const u16* __restrict__ wg1t_hi,
    const u16* __restrict__ wg1t_lo, u16* __restrict__ xb,
    float* __restrict__ p_buf) {
  __shared__ u16 Ah[2][128 * 32], Al[2][128 * 32];
  __shared__ u16 Bh[2][128 * 32], Bl[2][128 * 32];
  const int tid = threadIdx.x, lane = tid & 63, wid = tid >> 6;
  const int t0 = blockIdx.x * 128, n0 = blockIdx.y * 128;
  const int wm = wid >> 1, wn = wid & 1;
  const bool emit = (blockIdx.y == 0);
  const int arow = tid >> 1, akb = (tid & 1) * 16;   // A: 2 thr/row, 16 k each

  f32x4 acc[4][4];
  #pragma unroll
  for (int i = 0; i < 4; ++i)
    #pragma unroll
    for (int j = 0; j < 4; ++j) acc[i][j] = (f32x4){0.f, 0.f, 0.f, 0.f};

  // ---- prologue: stage kt=0 into buffer 0 ----
  stage_b32(Bh[0], wg1t_hi, n0, 0, wid, lane);
  stage_b32(Bl[0], wg1t_lo, n0, 0, wid, lane);
  {
    const float* src = x + (size_t)(t0 + arow) * 1024 + akb;
    #pragma unroll
    for (int i = 0; i < 4; ++i) {
      float4 v = *(const float4*)(src + i * 4);
      float vv[4] = {v.x, v.y, v.z, v.w};
      u16x4 h, l;
      u16 hh[4], ll[4];
      #pragma unroll
      for (int q = 0; q < 4; ++q) { hh[q] = f2bf(vv[q]); ll[q] = f2bf(vv[q] - bf2f(hh[q])); }
      h.x = hh[0]; h.y = hh[1]; h.z = hh[2]; h.w = hh[3];
      l.x = ll[0]; l.y = ll[1]; l.z = ll[2]; l.w = ll[3];
      *(u16x4*)&Ah[0][arow * 32 + akb + i * 4] = h;
      *(u16x4*)&Al[0][arow * 32 + akb + i * 4] = l;
      if (emit) *(u16x4*)(xb + (size_t)(t0 + arow) * 1024 + akb + i * 4) = h;
    }
  }
  __syncthreads();

  int cur = 0;
  for (int kt = 0; kt < 32; ++kt) {
    const bool has_next = kt < 31;
    const int nxt = cur ^ 1;
    float4 xv[4];
    if (has_next) {
      stage_b32(Bh[nxt], wg1t_hi, n0, (kt + 1) * 32, wid, lane);
      stage_b32(Bl[nxt], wg1t_lo, n0, (kt + 1) * 32, wid, lane);
      const float* src = x + (size_t)(t0 + arow) * 1024 + (kt + 1) * 32 + akb;
      #pragma unroll
      for (int i = 0; i < 4; ++i) xv[i] = *(const float4*)(src + i * 4);
    }
    // MFMA on cur: 3 terms
    {
      const int r = lane & 15, kq = (lane >> 4) * 8;
      bf16x8 ah[4], al[4], bh[4], bl[4];
      #pragma unroll
      for (int mf = 0; mf < 4; ++mf) {
        const int ro = (wm * 64 + mf * 16 + r) * 32 + kq;
        ah[mf] = *(const bf16x8*)&Ah[cur][ro];
        al[mf] = *(const bf16x8*)&Al[cur][ro];
      }
      #pragma unroll
      for (int nf = 0; nf < 4; ++nf) {
        const int ro = (wn * 64 + nf * 16 + r) * 32 + kq;
        bh[nf] = *(const bf16x8*)&Bh[cur][ro];
        bl[nf] = *(const bf16x8*)&Bl[cur][ro];
      }
      #pragma unroll
      for (int mf = 0; mf < 4; ++mf)
        #pragma unroll
        for (int nf = 0; nf < 4; ++nf) {
          acc[mf][nf] = __builtin_amdgcn_mfma_f32_16x16x32_bf16(ah[mf], bh[nf], acc[mf][nf], 0, 0, 0);
          acc[mf][nf] = __builtin_amdgcn_mfma_f32_16x16x32_bf16(ah[mf], bl[nf], acc[mf][nf], 0, 0, 0);
          acc[mf][nf] = __builtin_amdgcn_mfma_f32_16x16x32_bf16(al[mf], bh[nf], acc[mf][nf], 0, 0, 0);
        }
    }
    if (has_next) {
      #pragma unroll
      for (int i = 0; i < 4; ++i) {
        float vv[4] = {xv[i].x, xv[i].y, xv[i].z, xv[i].w};
        u16x4 h, l;
        u16 hh[4], ll[4];
        #pragma unroll
        for (int q = 0; q < 4; ++q) { hh[q] = f2bf(vv[q]); ll[q] = f2bf(vv[q] - bf2f(hh[q])); }
        h.x = hh[0]; h.y = hh[1]; h.z = hh[2]; h.w = hh[3];
        l.x = ll[0]; l.y = ll[1]; l.z = ll[2]; l.w = ll[3];
        *(u16x4*)&Ah[nxt][arow * 32 + akb + i * 4] = h;
        *(u16x4*)&Al[nxt][arow * 32 + akb + i * 4] = l;
        if (emit) *(u16x4*)(xb + (size_t)(t0 + arow) * 1024 + (kt + 1) * 32 + akb + i * 4) = h;
      }
    }
    __syncthreads();
    cur ^= 1;
  }

  // write raw GEMM1 output (bias/gelu applied in p2)
  #pragma unroll
  for (int mf = 0; mf < 4; ++mf)
    #pragma unroll
    for (int rr = 0; rr < 4; ++rr) {
      const int lt = wm * 64 + mf * 16 + ((lane >> 4) << 2) + rr;
      #pragma unroll
      for (int nf = 0; nf < 4; ++nf) {
        const int ln = wn * 64 + nf * 16 + (lane & 15);
        p_buf[(size_t)(t0 + lt) * 256 + n0 + ln] = acc[mf][nf][rr];
      }
    }
}

// ---------------- gating phase 2: bias + gelu + GEMM2 + softmax + top2 ----------------
__global__ __launch_bounds__(256) void gating_p2_kernel(
    const float* __restrict__ p_buf, const float* __restrict__ bg1,
    const float* __restrict__ wg2, const float* __restrict__ bg2,
    int* __restrict__ top_i, float2* __restrict__ top_g) {
  const int tid = threadIdx.x;
  const int tn = tid & 31, tm = tid >> 5;
  const int t0 = blockIdx.x * 32;

  float bb[8];
  {
    float4 ba = *(const float4*)&bg1[tn * 4];
    float4 bc = *(const float4*)&bg1[128 + tn * 4];
    bb[0] = ba.x; bb[1] = ba.y; bb[2] = ba.z; bb[3] = ba.w;
    bb[4] = bc.x; bb[5] = bc.y; bb[6] = bc.z; bb[7] = bc.w;
  }

  float hv[4][8];
  #pragma unroll
  for (int i = 0; i < 4; ++i) {
    const size_t t = t0 + tm * 4 + i;
    const float* p = &p_buf[t * 256];
    float4 a0 = *(const float4*)&p[tn * 4];
    float4 a1 = *(const float4*)&p[128 + tn * 4];
    hv[i][0] = gelu_exact(a0.x + bb[0]);
    hv[i][1] = gelu_exact(a0.y + bb[1]);
    hv[i][2] = gelu_exact(a0.z + bb[2]);
    hv[i][3] = gelu_exact(a0.w + bb[3]);
    hv[i][4] = gelu_exact(a1.x + bb[4]);
    hv[i][5] = gelu_exact(a1.y + bb[5]);
    hv[i][6] = gelu_exact(a1.z + bb[6]);
    hv[i][7] = gelu_exact(a1.w + bb[7]);
  }

  float part[4][8];
  #pragma unroll
  for (int i = 0; i < 4; ++i)
    #pragma unroll
    for (int e = 0; e < 8; ++e) part[i][e] = 0.f;
  #pragma unroll
  for (int j = 0; j < 8; ++j) {
    const int col = (j < 4) ? (tn * 4 + j) : (128 + tn * 4 + (j - 4));
    float4 wa = *(const float4*)&wg2[col * 8];
    float4 wb = *(const float4*)&wg2[col * 8 + 4];
    float we[8] = {wa.x, wa.y, wa.z, wa.w, wb.x, wb.y, wb.z, wb.w};
    #pragma unroll
    for (int i = 0; i < 4; ++i)
      #pragma unroll
      for (int e = 0; e < 8; ++e) part[i][e] += hv[i][j] * we[e];
  }
  #pragma unroll
  for (int mask = 1; mask < 32; mask <<= 1)
    #pragma unroll
    for (int i = 0; i < 4; ++i)
      #pragma unroll
      for (int e = 0; e < 8; ++e) part[i][e] += __shfl_xor(part[i][e], mask);

  if (tn < 4) {
    float lg[8];
    #pragma unroll
    for (int i = 0; i < 4; ++i)
      if (tn == i) {
        #pragma unroll
        for (int e = 0; e < 8; ++e) lg[e] = part[i][e];
      }
    #pragma unroll
    for (int e = 0; e < 8; ++e) lg[e] += bg2[e];
    float m = lg[0];
    #pragma unroll
    for (int e = 1; e < 8; ++e) m = fmaxf(m, lg[e]);
    float ex[8], s = 0.f;
    #pragma unroll
    for (int e = 0; e < 8; ++e) { ex[e] = expf(lg[e] - m); s += ex[e]; }
    int i1 = 0;
    #pragma unroll
    for (int e = 1; e < 8; ++e) if (lg[e] > lg[i1]) i1 = e;   // strict >: lowest idx on tie
    int i2 = (i1 == 0) ? 1 : 0;
    #pragma unroll
    for (int e = 0; e < 8; ++e) if (e != i1 && lg[e] > lg[i2]) i2 = e;
    float inv = 1.f / s;
    const int t = t0 + tm * 4 + tn;
    top_i[t] = i1 | (i2 << 8);
    top_g[t] = make_float2(ex[i1] * inv, ex[i2] * inv);
  }
}

// ---------------- hist: per-256-token-chunk expert histogram (LDS atomics only) ----------------
__global__ __launch_bounds__(256) void hist_kernel(const int* __restrict__ top_i,
                                                   int* __restrict__ hist) {
  __shared__ int h[NE];
  const int tid = threadIdx.x;
  if (tid < NE) h[tid] = 0;
  __syncthreads();
  const int ti = top_i[blockIdx.x * 256 + tid];
  atomicAdd(&h[ti & 255], 1);
  atomicAdd(&h[ti >> 8], 1);
  __syncthreads();
  if (tid < NE) hist[blockIdx.x * NE + tid] = h[tid];
}

// ---------------- scan: totals, padded offsets, per-chunk bases (single block) ----------------
__global__ __launch_bounds__(64) void scan_kernel(const int* __restrict__ hist,
                                                  int* __restrict__ cnt,
                                                  int* __restrict__ offs,
                                                  int* __restrict__ cbase) {
  __shared__ int tot[NE], off_s[NE];
  const int tid = threadIdx.x;
  if (tid < NE) {
    int s = 0;
    for (int c = 0; c < 64; ++c) s += hist[c * NE + tid];
    tot[tid] = s; cnt[tid] = s;
  }
  __syncthreads();
  if (tid == 0) {
    int o = 0;
    #pragma unroll
    for (int e = 0; e < NE; ++e) { off_s[e] = o; o += (tot[e] + 127) & ~127; }
  }
  __syncthreads();
  if (tid < NE) {
    offs[tid] = off_s[tid];
    int r = off_s[tid];
    for (int c = 0; c < 64; ++c) { cbase[c * NE + tid] = r; r += hist[c * NE + tid]; }
  }
}

// ---------------- fill: scatter tokens into per-expert compact lists (LDS atomics) ----------------
__global__ __launch_bounds__(256) void fill_kernel(
    const int* __restrict__ top_i, const int* __restrict__ cbase,
    int* __restrict__ tok_list, int* __restrict__ pos1, int* __restrict__ pos2) {
  __shared__ int lcnt[NE];
  const int tid = threadIdx.x;
  if (tid < NE) lcnt[tid] = 0;
  __syncthreads();
  const int t = blockIdx.x * 256 + tid;
  const int ti = top_i[t];
  const int i1 = ti & 255, i2 = ti >> 8;
  const int r1 = atomicAdd(&lcnt[i1], 1);
  const int r2 = atomicAdd(&lcnt[i2], 1);
  const int p1 = cbase[blockIdx.x * NE + i1] + r1;
  const int p2 = cbase[blockIdx.x * NE + i2] + r2;
  tok_list[p1] = t; tok_list[p2] = t;
  pos1[t] = p1; pos2[t] = p2;
}

// ---------------- pass A (compact): h[p][h] = gelu(x[tok[p]] @ W1e + b1e), bf16 ----------------
__global__ __launch_bounds__(256) void expert_h_kernel(
    const u16* __restrict__ xb, const u16* __restrict__ w1t,
    const float* __restrict__ b1, const int* __restrict__ tok_list,
    const int* __restrict__ cnt, const int* __restrict__ offs,
    u16* __restrict__ h_c) {
  __shared__ u16 As[128 * 64];
  __shared__ u16 Bs[128 * 64];
  __shared__ float b1_s[128];
  const int e = blockIdx.z;
  const int nblk = (cnt[e] + 127) >> 7;
  if ((int)blockIdx.x >= nblk) return;
  const int tid = threadIdx.x, lane = tid & 63, wid = tid >> 6;
  const int base = offs[e] + blockIdx.x * 128;
  const int n0 = blockIdx.y * 128;
  const int wm = wid >> 1, wn = wid & 1;

  if (tid < 128) b1_s[tid] = b1[e * 256 + n0 + tid];

  int tk[4];
  {
    const int r0 = wid * 8 + (lane >> 3);
    #pragma unroll
    for (int c = 0; c < 4; ++c) tk[c] = tok_list[base + r0 + 32 * c];
  }

  f32x4 acc[4][4];
  #pragma unroll
  for (int i = 0; i < 4; ++i)
    #pragma unroll
    for (int j = 0; j < 4; ++j) acc[i][j] = (f32x4){0.f, 0.f, 0.f, 0.f};

  const char* Bb = (const char*)w1t + ((size_t)e * 256 + n0) * 2048;
  const int cb = (lane & 7) * 16;
  for (int kt = 0; kt < 16; ++kt) {
    __syncthreads();
    {
      char* l = (char*)As + wid * 1024;
      #pragma unroll
      for (int c = 0; c < 4; ++c)
        gld16((const char*)xb + (size_t)tk[c] * 2048 + kt * 128 + cb, l + c * 4096);
    }
    stage_tile(Bs, Bb + kt * 128, 2048, wid, lane);
    __syncthreads();
    mma_step(As, Bs, acc, wm, wn, lane);
  }

  #pragma unroll
  for (int mf = 0; mf < 4; ++mf)
    #pragma unroll
    for (int rr = 0; rr < 4; ++rr) {
      const int lt = wm * 64 + mf * 16 + ((lane >> 4) << 2) + rr;
      #pragma unroll
      for (int nf = 0; nf < 4; ++nf) {
        const int ln = wn * 64 + nf * 16 + (lane & 15);
        float u = acc[mf][nf][rr] + b1_s[ln];
        h_c[(size_t)(base + lt) * 256 + n0 + ln] = f2bf(gelu_exact(u));
      }
    }
}

// ---------------- pass B (compact): o[p][d] = h[p] @ W2e + b2e, bf16 ----------------
__global__ __launch_bounds__(256) void moe_out_kernel(
    const u16* __restrict__ h_c, const u16* __restrict__ w2t,
    const float* __restrict__ b2, const int* __restrict__ cnt,
    const int* __restrict__ offs, u16* __restrict__ o_c) {
  __shared__ u16 As[128 * 64];
  __shared__ u16 Bs[128 * 64];
  __shared__ float b2_s[128];
  const int e = blockIdx.z;
  const int nblk = (cnt[e] + 127) >> 7;
  if ((int)blockIdx.x >= nblk) return;
  const int tid = threadIdx.x, lane = tid & 63, wid = tid >> 6;
  const int base = offs[e] + blockIdx.x * 128;
  const int n0 = blockIdx.y * 128;
  const int wm = wid >> 1, wn = wid & 1;

  if (tid < 128) b2_s[tid] = b2[(size_t)e * 1024 + n0 + tid];

  f32x4 acc[4][4];
  #pragma unroll
  for (int i = 0; i < 4; ++i)
    #pragma unroll
    for (int j = 0; j < 4; ++j) acc[i][j] = (f32x4){0.f, 0.f, 0.f, 0.f};

  const char* Ab = (const char*)h_c + (size_t)base * 512;
  const char* Bb = (const char*)w2t + ((size_t)e * D_DIM + n0) * 512;
  #pragma unroll 1
  for (int kt = 0; kt < 4; ++kt) {
    __syncthreads();
    stage_tile(As, Ab + kt * 128, 512, wid, lane);
    stage_tile(Bs, Bb + kt * 128, 512, wid, lane);
    __syncthreads();
    mma_step(As, Bs, acc, wm, wn, lane);
  }

  #pragma unroll
  for (int mf = 0; mf < 4; ++mf)
    #pragma unroll
    for (int rr = 0; rr < 4; ++rr) {
      const int lt = wm * 64 + mf * 16 + ((lane >> 4) << 2) + rr;
      #pragma unroll
      for (int nf = 0; nf < 4; ++nf) {
        const int ln = wn * 64 + nf * 16 + (lane & 15);
        o_c[(size_t)(base + lt) * 1024 + n0 + ln] = f2bf(acc[mf][nf][rr] + b2_s[ln]);
      }
    }
}

// ---------------- gather: y[t] = g1*o[p1] + g2*o[p2] ----------------
__global__ __launch_bounds__(256) void gather_kernel(
    const u16* __restrict__ o_c, const int* __restrict__ pos1,
    const int* __restrict__ pos2, const float2* __restrict__ top_g,
    float* __restrict__ y) {
  const int t = blockIdx.x;
  const int p1 = pos1[t], p2 = pos2[t];
  const float2 g = top_g[t];
  const int c = threadIdx.x * 4;
  u16x4 a = *(const u16x4*)&o_c[(size_t)p1 * 1024 + c];
  u16x4 b = *(const u16x4*)&o_c[(size_t)p2 * 1024 + c];
  float4 o;
  o.x = g.x * bf2f(a.x) + g.y * bf2f(b.x);
  o.y = g.x * bf2f(a.y) + g.y * bf2f(b.y);
  o.z = g.x * bf2f(a.z) + g.y * bf2f(b.z);
  o.w = g.x * bf2f(a.w) + g.y * bf2f(b.w);
  *(float4*)&y[(size_t)t * 1024 + c] = o;
}

extern "C" void kernel_launch(void* const* d_in, const int* in_sizes, int n_in,
                              void* d_out, int out_size, void* d_ws, size_t ws_size,
                              hipStream_t stream) {
  (void)in_sizes; (void)n_in; (void)out_size; (void)ws_size;
  const float* x   = (const float*)d_in[0];
  const float* wg1 = (const float*)d_in[1];
  const float* bg1 = (const float*)d_in[2];
  const float* wg2 = (const float*)d_in[3];
  const float* bg2 = (const float*)d_in[4];
  const float* w1  = (const float*)d_in[5];
  const float* b1  = (const float*)d_in[6];
  const float* w2  = (const float*)d_in[7];
  const float* b2  = (const float*)d_in[8];
  float* y = (float*)d_out;

  char* ws = (char*)d_ws;
  u16* xb   = (u16*)(ws);                 // 33,554,432 B
  u16* w1t  = (u16*)(ws + 33554432);      //  4,194,304 B
  u16* w2t  = (u16*)(ws + 37748736);      //  4,194,304 B
  char* M   = ws + 41943040;              // metadata block
  int*    cnt      = (int*)(M);                 // 32 B
  int*    offs     = (int*)(M + 64);            // 32 B
  int*    hist     = (int*)(M + 128);           // 2,048 B
  int*    cbase    = (int*)(M + 2304);          // 2,048 B
  int*    tok_list = (int*)(M + 4608);          // 135,168 B
  int*    top_i    = (int*)(M + 139776);        // 65,536 B
  float2* top_g    = (float2*)(M + 205312);     // 131,072 B
  int*    pos1     = (int*)(M + 336384);        // 65,536 B
  int*    pos2     = (int*)(M + 401920);        // 65,536 B
  u16* h_c = (u16*)(ws + 42467328);       // MAXP*256*2 = 17,301,504 B
  u16* o_c = (u16*)(ws + 59768832);       // MAXP*1024*2 = 69,206,016 B (ends 128,974,848)
  // Aliased onto o_c region (all dead before moe_out writes o_c):
  float* p_buf   = (float*)(ws + 59768832);          // [T][256] f32 = 16,777,216 B
  u16*   wg1t_hi = (u16*)(ws + 59768832 + 16777216); // 524,288 B
  u16*   wg1t_lo = (u16*)(ws + 59768832 + 17301504); // 524,288 B (ends 77,594,624)

  hipMemsetAsync(tok_list, 0, 135168, stream);  // pad slots -> token 0
  transpose_cvt_kernel<<<dim3(32, 8, 8), 256, 0, stream>>>(w1, w1t, 1024, 256);
  transpose_cvt_kernel<<<dim3(8, 32, 8), 256, 0, stream>>>(w2, w2t, 256, 1024);
  transpose_hilo_kernel<<<dim3(32, 8), 256, 0, stream>>>(wg1, wg1t_hi, wg1t_lo, 1024, 256);
  gating_mfma_kernel<<<dim3(128, 2), 256, 0, stream>>>(x, wg1t_hi, wg1t_lo, xb, p_buf);
  gating_p2_kernel<<<512, 256, 0, stream>>>(p_buf, bg1, wg2, bg2, top_i, top_g);
  hist_kernel<<<64, 256, 0, stream>>>(top_i, hist);
  scan_kernel<<<1, 64, 0, stream>>>(hist, cnt, offs, cbase);
  fill_kernel<<<64, 256, 0, stream>>>(top_i, cbase, tok_list, pos1, pos2);
  expert_h_kernel<<<dim3(128, 2, 8), 256, 0, stream>>>(xb, w1t, b1, tok_list, cnt, offs, h_c);
  moe_out_kernel <<<dim3(128, 8, 8), 256, 0, stream>>>(h_c, w2t, b2, cnt, offs, o_c);
  gather_kernel  <<<16384, 256, 0, stream>>>(o_c, pos1, pos2, top_g, y);
}

// Round 12
// 189.190 us; speedup vs baseline: 2.3702x; 1.1023x over previous
//
#include <hip/hip_runtime.h>

typedef unsigned short u16;
typedef __attribute__((ext_vector_type(8))) short bf16x8;
typedef __attribute__((ext_vector_type(4))) float f32x4;
typedef __attribute__((ext_vector_type(4))) u16 u16x4;

#define T_TOK 16384
#define D_DIM 1024
#define NE 8
#define MAXP 33792   // max padded compact rows: 2*T + 8*128

__device__ __forceinline__ u16 f2bf(float f) {
  union { float f; unsigned int u; } c; c.f = f;
  unsigned int u = c.u;
  u += 0x7fffu + ((u >> 16) & 1u);   // round-to-nearest-even
  return (u16)(u >> 16);
}

__device__ __forceinline__ float bf2f(u16 v) {
  union { unsigned int u; float f; } c; c.u = ((unsigned int)v) << 16;
  return c.f;
}

__device__ __forceinline__ float gelu_exact(float u) {
  return 0.5f * u * (1.0f + erff(u * 0.70710678118654752f));
}

__device__ __forceinline__ void gld16(const void* g, void* l) {
  __builtin_amdgcn_global_load_lds(
      (const __attribute__((address_space(1))) unsigned int*)g,
      (__attribute__((address_space(3))) unsigned int*)l, 16, 0, 0);
}

// Stage a 128-row x 64-col bf16 tile (contiguous rows) into linear LDS [128][64].
__device__ __forceinline__ void stage_tile(u16* lds, const char* g0, size_t stride,
                                           int wid, int lane) {
  const char* g = g0 + (size_t)(wid * 8 + (lane >> 3)) * stride + (size_t)((lane & 7) * 16);
  char* l = (char*)lds + wid * 1024;   // wave-uniform LDS base; HW adds lane*16
  #pragma unroll
  for (int c = 0; c < 4; ++c)
    gld16(g + (size_t)(32 * c) * stride, l + c * 4096);
}

// Stage a 128-row x 32-col bf16 tile (row stride 1024 bf16) into linear LDS [128][32].
__device__ __forceinline__ void stage_b32(u16* lds, const u16* mat, int rowbase,
                                          int k0, int wid, int lane) {
  const char* g0 = (const char*)(mat + (size_t)rowbase * 1024 + k0);
  #pragma unroll
  for (int c = 0; c < 2; ++c) {
    const int row = c * 64 + wid * 16 + (lane >> 2);
    const char* g = g0 + (size_t)row * 2048 + (size_t)((lane & 3) * 16);
    char* l = (char*)lds + c * 4096 + wid * 1024;   // + lane*16 by HW
    gld16(g, l);
  }
}

// One BK=64 step: 32 MFMA per wave, acc[4][4] (64x64 per wave, 2x2 waves = 128x128)
__device__ __forceinline__ void mma_step(const u16* As, const u16* Bs, f32x4 acc[4][4],
                                         int wm, int wn, int lane) {
  const int r = lane & 15, kq = (lane >> 4) * 8;
  #pragma unroll
  for (int ks = 0; ks < 2; ++ks) {
    const int col = ks * 32 + kq;
    bf16x8 a[4], b[4];
    #pragma unroll
    for (int mf = 0; mf < 4; ++mf)
      a[mf] = *(const bf16x8*)&As[(wm * 64 + mf * 16 + r) * 64 + col];
    #pragma unroll
    for (int nf = 0; nf < 4; ++nf)
      b[nf] = *(const bf16x8*)&Bs[(wn * 64 + nf * 16 + r) * 64 + col];
    #pragma unroll
    for (int mf = 0; mf < 4; ++mf)
      #pragma unroll
      for (int nf = 0; nf < 4; ++nf)
        acc[mf][nf] = __builtin_amdgcn_mfma_f32_16x16x32_bf16(a[mf], b[nf], acc[mf][nf], 0, 0, 0);
  }
}

// ---------------- tiled transpose+convert: in[e][R][C] f32 -> out[e][C][R] bf16 ----------------
__global__ __launch_bounds__(256) void transpose_cvt_kernel(const float* __restrict__ in,
                                                            u16* __restrict__ out,
                                                            int R, int C) {
  __shared__ u16 t[32][36];
  const int e = blockIdx.z;
  const int r0 = blockIdx.x * 32, c0 = blockIdx.y * 32;
  const int tid = threadIdx.x;
  {
    const int r = tid >> 3, cq = (tid & 7) * 4;
    float4 v = *(const float4*)(in + ((size_t)e * R + r0 + r) * C + c0 + cq);
    t[r][cq + 0] = f2bf(v.x); t[r][cq + 1] = f2bf(v.y);
    t[r][cq + 2] = f2bf(v.z); t[r][cq + 3] = f2bf(v.w);
  }
  __syncthreads();
  {
    const int c = tid >> 3, rq = (tid & 7) * 4;
    u16x4 o;
    o.x = t[rq + 0][c]; o.y = t[rq + 1][c]; o.z = t[rq + 2][c]; o.w = t[rq + 3][c];
    *(u16x4*)(out + ((size_t)e * C + c0 + c) * R + r0 + rq) = o;
  }
}

// ---------------- transpose+split-convert: in[R][C] f32 -> hi/lo [C][R] bf16 ----------------
__global__ __launch_bounds__(256) void transpose_hilo_kernel(const float* __restrict__ in,
                                                             u16* __restrict__ out_hi,
                                                             u16* __restrict__ out_lo,
                                                             int R, int C) {
  __shared__ u16 th[32][36];
  __shared__ u16 tl[32][36];
  const int r0 = blockIdx.x * 32, c0 = blockIdx.y * 32;
  const int tid = threadIdx.x;
  {
    const int r = tid >> 3, cq = (tid & 7) * 4;
    float4 v = *(const float4*)(in + (size_t)(r0 + r) * C + c0 + cq);
    float vv[4] = {v.x, v.y, v.z, v.w};
    #pragma unroll
    for (int i = 0; i < 4; ++i) {
      u16 h = f2bf(vv[i]);
      th[r][cq + i] = h;
      tl[r][cq + i] = f2bf(vv[i] - bf2f(h));
    }
  }
  __syncthreads();
  {
    const int c = tid >> 3, rq = (tid & 7) * 4;
    u16x4 oh, ol;
    oh.x = th[rq + 0][c]; oh.y = th[rq + 1][c]; oh.z = th[rq + 2][c]; oh.w = th[rq + 3][c];
    ol.x = tl[rq + 0][c]; ol.y = tl[rq + 1][c]; ol.z = tl[rq + 2][c]; ol.w = tl[rq + 3][c];
    *(u16x4*)(out_hi + (size_t)(c0 + c) * R + r0 + rq) = oh;
    *(u16x4*)(out_lo + (size_t)(c0 + c) * R + r0 + rq) = ol;
  }
}

// ---------------- gating GEMM1 via split-bf16 MFMA (3-term), K-split x2 ----------------
// grid (128, 2, 2): x = 128-token tile, y = n-half, z = K-half (512 K each).
// BK=32 double-buffered. A (x) reg-staged with on-the-fly hi/lo split; emits its
// K-half of xb when blockIdx.y==0. acc = Ah*Bh + Ah*Bl + Al*Bh (fp32 MFMA).
// Writes p_buf[kh][t][n] partials; p2 sums the two halves.
__global__ __launch_bounds__(256) void gating_mfma_kernel(
    const float* __restrict__ x, const u16* __restrict__ wg1t_hi,
    const u16* __restrict__ wg1t_lo, u16* __restrict__ xb,
    float* __restrict__ p_buf) {
  __shared__ u16 Ah[2][128 * 32], Al[2][128 * 32];
  __shared__ u16 Bh[2][128 * 32], Bl[2][128 * 32];
  const int tid = threadIdx.x, lane = tid & 63, wid = tid >> 6;
  const int t0 = blockIdx.x * 128, n0 = blockIdx.y * 128;
  const int kh = blockIdx.z, kbeg = kh * 512;
  const int wm = wid >> 1, wn = wid & 1;
  const bool emit = (blockIdx.y == 0);
  const int arow = tid >> 1, akb = (tid & 1) * 16;   // A: 2 thr/row, 16 k each

  f32x4 acc[4][4];
  #pragma unroll
  for (int i = 0; i < 4; ++i)
    #pragma unroll
    for (int j = 0; j < 4; ++j) acc[i][j] = (f32x4){0.f, 0.f, 0.f, 0.f};

  // ---- prologue: stage kt=0 into buffer 0 ----
  stage_b32(Bh[0], wg1t_hi, n0, kbeg, wid, lane);
  stage_b32(Bl[0], wg1t_lo, n0, kbeg, wid, lane);
  {
    const float* src = x + (size_t)(t0 + arow) * 1024 + kbeg + akb;
    #pragma unroll
    for (int i = 0; i < 4; ++i) {
      float4 v = *(const float4*)(src + i * 4);
      float vv[4] = {v.x, v.y, v.z, v.w};
      u16x4 h, l;
      u16 hh[4], ll[4];
      #pragma unroll
      for (int q = 0; q < 4; ++q) { hh[q] = f2bf(vv[q]); ll[q] = f2bf(vv[q] - bf2f(hh[q])); }
      h.x = hh[0]; h.y = hh[1]; h.z = hh[2]; h.w = hh[3];
      l.x = ll[0]; l.y = ll[1]; l.z = ll[2]; l.w = ll[3];
      *(u16x4*)&Ah[0][arow * 32 + akb + i * 4] = h;
      *(u16x4*)&Al[0][arow * 32 + akb + i * 4] = l;
      if (emit) *(u16x4*)(xb + (size_t)(t0 + arow) * 1024 + kbeg + akb + i * 4) = h;
    }
  }
  __syncthreads();

  int cur = 0;
  for (int kt = 0; kt < 16; ++kt) {
    const bool has_next = kt < 15;
    const int nxt = cur ^ 1;
    float4 xv[4];
    if (has_next) {
      stage_b32(Bh[nxt], wg1t_hi, n0, kbeg + (kt + 1) * 32, wid, lane);
      stage_b32(Bl[nxt], wg1t_lo, n0, kbeg + (kt + 1) * 32, wid, lane);
      const float* src = x + (size_t)(t0 + arow) * 1024 + kbeg + (kt + 1) * 32 + akb;
      #pragma unroll
      for (int i = 0; i < 4; ++i) xv[i] = *(const float4*)(src + i * 4);
    }
    // MFMA on cur: 3 terms
    {
      const int r = lane & 15, kq = (lane >> 4) * 8;
      bf16x8 ah[4], al[4], bh[4], bl[4];
      #pragma unroll
      for (int mf = 0; mf < 4; ++mf) {
        const int ro = (wm * 64 + mf * 16 + r) * 32 + kq;
        ah[mf] = *(const bf16x8*)&Ah[cur][ro];
        al[mf] = *(const bf16x8*)&Al[cur][ro];
      }
      #pragma unroll
      for (int nf = 0; nf < 4; ++nf) {
        const int ro = (wn * 64 + nf * 16 + r) * 32 + kq;
        bh[nf] = *(const bf16x8*)&Bh[cur][ro];
        bl[nf] = *(const bf16x8*)&Bl[cur][ro];
      }
      #pragma unroll
      for (int mf = 0; mf < 4; ++mf)
        #pragma unroll
        for (int nf = 0; nf < 4; ++nf) {
          acc[mf][nf] = __builtin_amdgcn_mfma_f32_16x16x32_bf16(ah[mf], bh[nf], acc[mf][nf], 0, 0, 0);
          acc[mf][nf] = __builtin_amdgcn_mfma_f32_16x16x32_bf16(ah[mf], bl[nf], acc[mf][nf], 0, 0, 0);
          acc[mf][nf] = __builtin_amdgcn_mfma_f32_16x16x32_bf16(al[mf], bh[nf], acc[mf][nf], 0, 0, 0);
        }
    }
    if (has_next) {
      #pragma unroll
      for (int i = 0; i < 4; ++i) {
        float vv[4] = {xv[i].x, xv[i].y, xv[i].z, xv[i].w};
        u16x4 h, l;
        u16 hh[4], ll[4];
        #pragma unroll
        for (int q = 0; q < 4; ++q) { hh[q] = f2bf(vv[q]); ll[q] = f2bf(vv[q] - bf2f(hh[q])); }
        h.x = hh[0]; h.y = hh[1]; h.z = hh[2]; h.w = hh[3];
        l.x = ll[0]; l.y = ll[1]; l.z = ll[2]; l.w = ll[3];
        *(u16x4*)&Ah[nxt][arow * 32 + akb + i * 4] = h;
        *(u16x4*)&Al[nxt][arow * 32 + akb + i * 4] = l;
        if (emit)
          *(u16x4*)(xb + (size_t)(t0 + arow) * 1024 + kbeg + (kt + 1) * 32 + akb + i * 4) = h;
      }
    }
    __syncthreads();
    cur ^= 1;
  }

  // write raw partial GEMM1 output (bias/gelu in p2)
  #pragma unroll
  for (int mf = 0; mf < 4; ++mf)
    #pragma unroll
    for (int rr = 0; rr < 4; ++rr) {
      const int lt = wm * 64 + mf * 16 + ((lane >> 4) << 2) + rr;
      #pragma unroll
      for (int nf = 0; nf < 4; ++nf) {
        const int ln = wn * 64 + nf * 16 + (lane & 15);
        p_buf[((size_t)kh * T_TOK + t0 + lt) * 256 + n0 + ln] = acc[mf][nf][rr];
      }
    }
}

// ---------------- gating phase 2: sum 2 partials + bias + gelu + GEMM2 + softmax + top2 ----------------
__global__ __launch_bounds__(256) void gating_p2_kernel(
    const float* __restrict__ p_buf, const float* __restrict__ bg1,
    const float* __restrict__ wg2, const float* __restrict__ bg2,
    int* __restrict__ top_i, float2* __restrict__ top_g) {
  const int tid = threadIdx.x;
  const int tn = tid & 31, tm = tid >> 5;
  const int t0 = blockIdx.x * 32;

  float bb[8];
  {
    float4 ba = *(const float4*)&bg1[tn * 4];
    float4 bc = *(const float4*)&bg1[128 + tn * 4];
    bb[0] = ba.x; bb[1] = ba.y; bb[2] = ba.z; bb[3] = ba.w;
    bb[4] = bc.x; bb[5] = bc.y; bb[6] = bc.z; bb[7] = bc.w;
  }

  float hv[4][8];
  #pragma unroll
  for (int i = 0; i < 4; ++i) {
    const size_t t = t0 + tm * 4 + i;
    const float* pa = &p_buf[t * 256];
    const float* pb = &p_buf[((size_t)T_TOK + t) * 256];
    float4 a0 = *(const float4*)&pa[tn * 4];
    float4 a1 = *(const float4*)&pa[128 + tn * 4];
    float4 b0 = *(const float4*)&pb[tn * 4];
    float4 b1 = *(const float4*)&pb[128 + tn * 4];
    hv[i][0] = gelu_exact(a0.x + b0.x + bb[0]);
    hv[i][1] = gelu_exact(a0.y + b0.y + bb[1]);
    hv[i][2] = gelu_exact(a0.z + b0.z + bb[2]);
    hv[i][3] = gelu_exact(a0.w + b0.w + bb[3]);
    hv[i][4] = gelu_exact(a1.x + b1.x + bb[4]);
    hv[i][5] = gelu_exact(a1.y + b1.y + bb[5]);
    hv[i][6] = gelu_exact(a1.z + b1.z + bb[6]);
    hv[i][7] = gelu_exact(a1.w + b1.w + bb[7]);
  }

  float part[4][8];
  #pragma unroll
  for (int i = 0; i < 4; ++i)
    #pragma unroll
    for (int e = 0; e < 8; ++e) part[i][e] = 0.f;
  #pragma unroll
  for (int j = 0; j < 8; ++j) {
    const int col = (j < 4) ? (tn * 4 + j) : (128 + tn * 4 + (j - 4));
    float4 wa = *(const float4*)&wg2[col * 8];
    float4 wb = *(const float4*)&wg2[col * 8 + 4];
    float we[8] = {wa.x, wa.y, wa.z, wa.w, wb.x, wb.y, wb.z, wb.w};
    #pragma unroll
    for (int i = 0; i < 4; ++i)
      #pragma unroll
      for (int e = 0; e < 8; ++e) part[i][e] += hv[i][j] * we[e];
  }
  #pragma unroll
  for (int mask = 1; mask < 32; mask <<= 1)
    #pragma unroll
    for (int i = 0; i < 4; ++i)
      #pragma unroll
      for (int e = 0; e < 8; ++e) part[i][e] += __shfl_xor(part[i][e], mask);

  if (tn < 4) {
    float lg[8];
    #pragma unroll
    for (int i = 0; i < 4; ++i)
      if (tn == i) {
        #pragma unroll
        for (int e = 0; e < 8; ++e) lg[e] = part[i][e];
      }
    #pragma unroll
    for (int e = 0; e < 8; ++e) lg[e] += bg2[e];
    float m = lg[0];
    #pragma unroll
    for (int e = 1; e < 8; ++e) m = fmaxf(m, lg[e]);
    float ex[8], s = 0.f;
    #pragma unroll
    for (int e = 0; e < 8; ++e) { ex[e] = expf(lg[e] - m); s += ex[e]; }
    int i1 = 0;
    #pragma unroll
    for (int e = 1; e < 8; ++e) if (lg[e] > lg[i1]) i1 = e;   // strict >: lowest idx on tie
    int i2 = (i1 == 0) ? 1 : 0;
    #pragma unroll
    for (int e = 0; e < 8; ++e) if (e != i1 && lg[e] > lg[i2]) i2 = e;
    float inv = 1.f / s;
    const int t = t0 + tm * 4 + tn;
    top_i[t] = i1 | (i2 << 8);
    top_g[t] = make_float2(ex[i1] * inv, ex[i2] * inv);
  }
}

// ---------------- hist: per-256-token-chunk expert histogram (LDS atomics only) ----------------
__global__ __launch_bounds__(256) void hist_kernel(const int* __restrict__ top_i,
                                                   int* __restrict__ hist) {
  __shared__ int h[NE];
  const int tid = threadIdx.x;
  if (tid < NE) h[tid] = 0;
  __syncthreads();
  const int ti = top_i[blockIdx.x * 256 + tid];
  atomicAdd(&h[ti & 255], 1);
  atomicAdd(&h[ti >> 8], 1);
  __syncthreads();
  if (tid < NE) hist[blockIdx.x * NE + tid] = h[tid];
}

// ---------------- scan: totals, padded offsets, per-chunk bases (single block) ----------------
__global__ __launch_bounds__(64) void scan_kernel(const int* __restrict__ hist,
                                                  int* __restrict__ cnt,
                                                  int* __restrict__ offs,
                                                  int* __restrict__ cbase) {
  __shared__ int tot[NE], off_s[NE];
  const int tid = threadIdx.x;
  if (tid < NE) {
    int s = 0;
    for (int c = 0; c < 64; ++c) s += hist[c * NE + tid];
    tot[tid] = s; cnt[tid] = s;
  }
  __syncthreads();
  if (tid == 0) {
    int o = 0;
    #pragma unroll
    for (int e = 0; e < NE; ++e) { off_s[e] = o; o += (tot[e] + 127) & ~127; }
  }
  __syncthreads();
  if (tid < NE) {
    offs[tid] = off_s[tid];
    int r = off_s[tid];
    for (int c = 0; c < 64; ++c) { cbase[c * NE + tid] = r; r += hist[c * NE + tid]; }
  }
}

// ---------------- fill: scatter tokens into per-expert compact lists (LDS atomics) ----------------
__global__ __launch_bounds__(256) void fill_kernel(
    const int* __restrict__ top_i, const int* __restrict__ cbase,
    int* __restrict__ tok_list, int* __restrict__ pos1, int* __restrict__ pos2) {
  __shared__ int lcnt[NE];
  const int tid = threadIdx.x;
  if (tid < NE) lcnt[tid] = 0;
  __syncthreads();
  const int t = blockIdx.x * 256 + tid;
  const int ti = top_i[t];
  const int i1 = ti & 255, i2 = ti >> 8;
  const int r1 = atomicAdd(&lcnt[i1], 1);
  const int r2 = atomicAdd(&lcnt[i2], 1);
  const int p1 = cbase[blockIdx.x * NE + i1] + r1;
  const int p2 = cbase[blockIdx.x * NE + i2] + r2;
  tok_list[p1] = t; tok_list[p2] = t;
  pos1[t] = p1; pos2[t] = p2;
}

// ---------------- pass A (compact, BM=64): h[p][h] = gelu(x[tok[p]] @ W1e + b1e) ----------------
// grid (256, 2, 8): 64-row compact tiles -> ~1024 active blocks (4/CU). 4 waves as
// 2x2, each wave 32x64 of the 64x128 tile. acc[2][4] (32 VGPR) — no min-waves bound.
__global__ __launch_bounds__(256) void expert_h_kernel(
    const u16* __restrict__ xb, const u16* __restrict__ w1t,
    const float* __restrict__ b1, const int* __restrict__ tok_list,
    const int* __restrict__ cnt, const int* __restrict__ offs,
    u16* __restrict__ h_c) {
  __shared__ u16 As[64 * 64];
  __shared__ u16 Bs[128 * 64];
  __shared__ float b1_s[128];
  const int e = blockIdx.z;
  const int nblk = (cnt[e] + 63) >> 6;
  if ((int)blockIdx.x >= nblk) return;
  const int tid = threadIdx.x, lane = tid & 63, wid = tid >> 6;
  const int base = offs[e] + blockIdx.x * 64;
  const int n0 = blockIdx.y * 128;
  const int wm = wid >> 1, wn = wid & 1;

  if (tid < 128) b1_s[tid] = b1[e * 256 + n0 + tid];

  // token ids for this wave's two staged 8-row chunks (chunk q = wid*2+c)
  int tk[2];
  #pragma unroll
  for (int c = 0; c < 2; ++c)
    tk[c] = tok_list[base + (wid * 2 + c) * 8 + (lane >> 3)];

  f32x4 acc[2][4];
  #pragma unroll
  for (int i = 0; i < 2; ++i)
    #pragma unroll
    for (int j = 0; j < 4; ++j) acc[i][j] = (f32x4){0.f, 0.f, 0.f, 0.f};

  const char* Bb = (const char*)w1t + ((size_t)e * 256 + n0) * 2048;
  const int cb = (lane & 7) * 16;
  for (int kt = 0; kt < 16; ++kt) {
    __syncthreads();
    {   // gather-stage A [64][64]: per-lane global row = tok_list row
      char* l = (char*)As + wid * 2048;
      #pragma unroll
      for (int c = 0; c < 2; ++c)
        gld16((const char*)xb + (size_t)tk[c] * 2048 + kt * 128 + cb, l + c * 1024);
    }
    stage_tile(Bs, Bb + kt * 128, 2048, wid, lane);
    __syncthreads();
    {   // 64x128 mma: wave (wm,wn) does 32x64, 16 MFMA/kt
      const int r = lane & 15, kq = (lane >> 4) * 8;
      #pragma unroll
      for (int ks = 0; ks < 2; ++ks) {
        const int col = ks * 32 + kq;
        bf16x8 a[2], b[4];
        #pragma unroll
        for (int mf = 0; mf < 2; ++mf)
          a[mf] = *(const bf16x8*)&As[(wm * 32 + mf * 16 + r) * 64 + col];
        #pragma unroll
        for (int nf = 0; nf < 4; ++nf)
          b[nf] = *(const bf16x8*)&Bs[(wn * 64 + nf * 16 + r) * 64 + col];
        #pragma unroll
        for (int mf = 0; mf < 2; ++mf)
          #pragma unroll
          for (int nf = 0; nf < 4; ++nf)
            acc[mf][nf] = __builtin_amdgcn_mfma_f32_16x16x32_bf16(a[mf], b[nf], acc[mf][nf], 0, 0, 0);
      }
    }
  }

  #pragma unroll
  for (int mf = 0; mf < 2; ++mf)
    #pragma unroll
    for (int rr = 0; rr < 4; ++rr) {
      const int lt = wm * 32 + mf * 16 + ((lane >> 4) << 2) + rr;
      #pragma unroll
      for (int nf = 0; nf < 4; ++nf) {
        const int ln = wn * 64 + nf * 16 + (lane & 15);
        float u = acc[mf][nf][rr] + b1_s[ln];
        h_c[(size_t)(base + lt) * 256 + n0 + ln] = f2bf(gelu_exact(u));
      }
    }
}

// ---------------- pass B (compact): o[p][d] = h[p] @ W2e + b2e, bf16 ----------------
__global__ __launch_bounds__(256) void moe_out_kernel(
    const u16* __restrict__ h_c, const u16* __restrict__ w2t,
    const float* __restrict__ b2, const int* __restrict__ cnt,
    const int* __restrict__ offs, u16* __restrict__ o_c) {
  __shared__ u16 As[128 * 64];
  __shared__ u16 Bs[128 * 64];
  __shared__ float b2_s[128];
  const int e = blockIdx.z;
  const int nblk = (cnt[e] + 127) >> 7;
  if ((int)blockIdx.x >= nblk) return;
  const int tid = threadIdx.x, lane = tid & 63, wid = tid >> 6;
  const int base = offs[e] + blockIdx.x * 128;
  const int n0 = blockIdx.y * 128;
  const int wm = wid >> 1, wn = wid & 1;

  if (tid < 128) b2_s[tid] = b2[(size_t)e * 1024 + n0 + tid];

  f32x4 acc[4][4];
  #pragma unroll
  for (int i = 0; i < 4; ++i)
    #pragma unroll
    for (int j = 0; j < 4; ++j) acc[i][j] = (f32x4){0.f, 0.f, 0.f, 0.f};

  const char* Ab = (const char*)h_c + (size_t)base * 512;
  const char* Bb = (const char*)w2t + ((size_t)e * D_DIM + n0) * 512;
  #pragma unroll 1
  for (int kt = 0; kt < 4; ++kt) {
    __syncthreads();
    stage_tile(As, Ab + kt * 128, 512, wid, lane);
    stage_tile(Bs, Bb + kt * 128, 512, wid, lane);
    __syncthreads();
    mma_step(As, Bs, acc, wm, wn, lane);
  }

  #pragma unroll
  for (int mf = 0; mf < 4; ++mf)
    #pragma unroll
    for (int rr = 0; rr < 4; ++rr) {
      const int lt = wm * 64 + mf * 16 + ((lane >> 4) << 2) + rr;
      #pragma unroll
      for (int nf = 0; nf < 4; ++nf) {
        const int ln = wn * 64 + nf * 16 + (lane & 15);
        o_c[(size_t)(base + lt) * 1024 + n0 + ln] = f2bf(acc[mf][nf][rr] + b2_s[ln]);
      }
    }
}

// ---------------- gather: y[t] = g1*o[p1] + g2*o[p2] ----------------
__global__ __launch_bounds__(256) void gather_kernel(
    const u16* __restrict__ o_c, const int* __restrict__ pos1,
    const int* __restrict__ pos2, const float2* __restrict__ top_g,
    float* __restrict__ y) {
  const int t = blockIdx.x;
  const int p1 = pos1[t], p2 = pos2[t];
  const float2 g = top_g[t];
  const int c = threadIdx.x * 4;
  u16x4 a = *(const u16x4*)&o_c[(size_t)p1 * 1024 + c];
  u16x4 b = *(const u16x4*)&o_c[(size_t)p2 * 1024 + c];
  float4 o;
  o.x = g.x * bf2f(a.x) + g.y * bf2f(b.x);
  o.y = g.x * bf2f(a.y) + g.y * bf2f(b.y);
  o.z = g.x * bf2f(a.z) + g.y * bf2f(b.z);
  o.w = g.x * bf2f(a.w) + g.y * bf2f(b.w);
  *(float4*)&y[(size_t)t * 1024 + c] = o;
}

extern "C" void kernel_launch(void* const* d_in, const int* in_sizes, int n_in,
                              void* d_out, int out_size, void* d_ws, size_t ws_size,
                              hipStream_t stream) {
  (void)in_sizes; (void)n_in; (void)out_size; (void)ws_size;
  const float* x   = (const float*)d_in[0];
  const float* wg1 = (const float*)d_in[1];
  const float* bg1 = (const float*)d_in[2];
  const float* wg2 = (const float*)d_in[3];
  const float* bg2 = (const float*)d_in[4];
  const float* w1  = (const float*)d_in[5];
  const float* b1  = (const float*)d_in[6];
  const float* w2  = (const float*)d_in[7];
  const float* b2  = (const float*)d_in[8];
  float* y = (float*)d_out;

  char* ws = (char*)d_ws;
  u16* xb   = (u16*)(ws);                 // 33,554,432 B
  u16* w1t  = (u16*)(ws + 33554432);      //  4,194,304 B
  u16* w2t  = (u16*)(ws + 37748736);      //  4,194,304 B
  char* M   = ws + 41943040;              // metadata block
  int*    cnt      = (int*)(M);                 // 32 B
  int*    offs     = (int*)(M + 64);            // 32 B
  int*    hist     = (int*)(M + 128);           // 2,048 B
  int*    cbase    = (int*)(M + 2304);          // 2,048 B
  int*    tok_list = (int*)(M + 4608);          // 135,168 B
  int*    top_i    = (int*)(M + 139776);        // 65,536 B
  float2* top_g    = (float2*)(M + 205312);     // 131,072 B
  int*    pos1     = (int*)(M + 336384);        // 65,536 B
  int*    pos2     = (int*)(M + 401920);        // 65,536 B
  u16* h_c = (u16*)(ws + 42467328);       // MAXP*256*2 = 17,301,504 B
  u16* o_c = (u16*)(ws + 59768832);       // MAXP*1024*2 = 69,206,016 B (ends 128,974,848)
  // Aliased onto o_c region (all dead before moe_out writes o_c):
  float* p_buf   = (float*)(ws + 59768832);          // [2][T][256] f32 = 33,554,432 B
  u16*   wg1t_hi = (u16*)(ws + 93323264);            // 524,288 B
  u16*   wg1t_lo = (u16*)(ws + 93847552);            // 524,288 B (ends 94,371,840)

  hipMemsetAsync(tok_list, 0, 135168, stream);  // pad slots -> token 0
  transpose_cvt_kernel<<<dim3(32, 8, 8), 256, 0, stream>>>(w1, w1t, 1024, 256);
  transpose_cvt_kernel<<<dim3(8, 32, 8), 256, 0, stream>>>(w2, w2t, 256, 1024);
  transpose_hilo_kernel<<<dim3(32, 8), 256, 0, stream>>>(wg1, wg1t_hi, wg1t_lo, 1024, 256);
  gating_mfma_kernel<<<dim3(128, 2, 2), 256, 0, stream>>>(x, wg1t_hi, wg1t_lo, xb, p_buf);
  gating_p2_kernel<<<512, 256, 0, stream>>>(p_buf, bg1, wg2, bg2, top_i, top_g);
  hist_kernel<<<64, 256, 0, stream>>>(top_i, hist);
  scan_kernel<<<1, 64, 0, stream>>>(hist, cnt, offs, cbase);
  fill_kernel<<<64, 256, 0, stream>>>(top_i, cbase, tok_list, pos1, pos2);
  expert_h_kernel<<<dim3(256, 2, 8), 256, 0, stream>>>(xb, w1t, b1, tok_list, cnt, offs, h_c);
  moe_out_kernel <<<dim3(128, 8, 8), 256, 0, stream>>>(h_c, w2t, b2, cnt, offs, o_c);
  gather_kernel  <<<16384, 256, 0, stream>>>(o_c, pos1, pos2, top_g, y);
}